// Round 1
// baseline (912.771 us; speedup 1.0000x reference)
//
#include <hip/hip_runtime.h>
#include <stdint.h>

typedef unsigned short ushort_t;
typedef __bf16 bf16_t;
typedef __attribute__((ext_vector_type(8))) __bf16 bf16x8;
typedef __attribute__((ext_vector_type(4))) float f32x4;

#define MFMA16(a, b, c) __builtin_amdgcn_mfma_f32_16x16x32_bf16((a), (b), (c), 0, 0, 0)

__device__ __forceinline__ ushort_t f2bf(float f) {
    unsigned u = __float_as_uint(f);
    u += 0x7fffu + ((u >> 16) & 1u);   // round-to-nearest-even
    return (ushort_t)(u >> 16);
}
__device__ __forceinline__ float bf2f(ushort_t h) {
    return __uint_as_float(((unsigned)h) << 16);
}

// ---------------------------------------------------------------- cast f32 -> bf16
__global__ __launch_bounds__(256) void cast_f32_bf16(const float* __restrict__ in,
                                                     ushort_t* __restrict__ out, int n4) {
    int i = blockIdx.x * 256 + threadIdx.x;
    if (i < n4) {
        float4 v = ((const float4*)in)[i];
        ushort4 o;
        o.x = f2bf(v.x); o.y = f2bf(v.y); o.z = f2bf(v.z); o.w = f2bf(v.w);
        ((ushort4*)out)[i] = o;
    }
}

// ---------------------------------------------------------------- RoPE (in-place, bf16)
// X is (2048, ppr*2); pair p -> head h=p/64, j=p%64; cols h*128+2j, h*128+2j+1
__global__ __launch_bounds__(256) void rope_kernel(ushort_t* __restrict__ X,
                                                   const float* __restrict__ cs,
                                                   const float* __restrict__ sn,
                                                   int ppr, float scale, int total) {
    int idx = blockIdx.x * 256 + threadIdx.x;
    if (idx >= total) return;
    int t = idx / ppr;
    int p = idx - t * ppr;
    int h = p >> 6, j = p & 63;
    int c0 = h * 128 + j * 2;
    ushort_t* row = X + (size_t)t * (ppr * 2);
    float x1 = bf2f(row[c0]), x2 = bf2f(row[c0 + 1]);
    float c = cs[t * 64 + j], s = sn[t * 64 + j];
    row[c0]     = f2bf((x1 * c - x2 * s) * scale);
    row[c0 + 1] = f2bf((x1 * s + x2 * c) * scale);
}

// ---------------------------------------------------------------- GEMM: C = A @ B^T
// A (M,K) bf16 row-major, B (N,K) bf16 row-major. 128x128 tile, BK=32, 4 waves.
// blockIdx.z selects (B0,C0) or (B1,C1) so K and V projections share one launch.
__device__ __forceinline__ void store_out(ushort_t* p, float v) { *p = f2bf(v); }
__device__ __forceinline__ void store_out(float* p, float v) { *p = v; }

template <typename OutT>
__global__ __launch_bounds__(256) void gemm_bt(const ushort_t* __restrict__ A,
                                               const ushort_t* __restrict__ B0,
                                               const ushort_t* __restrict__ B1,
                                               OutT* __restrict__ C0, OutT* __restrict__ C1,
                                               int M, int N, int K) {
    const ushort_t* B = (blockIdx.z == 0) ? B0 : B1;
    OutT* C = (blockIdx.z == 0) ? C0 : C1;
    const int bm = blockIdx.x * 128, bn = blockIdx.y * 128;
    __shared__ ushort_t As[128 * 40];   // pad 32->40 to break bank conflicts
    __shared__ ushort_t Bs[128 * 40];
    const int tid = threadIdx.x;
    const int w = tid >> 6, lane = tid & 63;
    const int quad = lane >> 4, l16 = lane & 15;
    const int wm = (w >> 1) * 64, wn = (w & 1) * 64;
    f32x4 acc[4][4] = {};

    const int srow = tid >> 2;          // 0..63
    const int scol = (tid & 3) * 8;     // 0,8,16,24 — 4 lanes cover a 64B row chunk
    const ushort_t* Ag = A + (size_t)(bm + srow) * K + scol;
    const ushort_t* Bg = B + (size_t)(bn + srow) * K + scol;

    for (int k0 = 0; k0 < K; k0 += 32) {
        uint4 a0 = *(const uint4*)(Ag + k0);
        uint4 a1 = *(const uint4*)(Ag + (size_t)64 * K + k0);
        uint4 b0 = *(const uint4*)(Bg + k0);
        uint4 b1 = *(const uint4*)(Bg + (size_t)64 * K + k0);
        *(uint4*)(&As[srow * 40 + scol]) = a0;
        *(uint4*)(&As[(srow + 64) * 40 + scol]) = a1;
        *(uint4*)(&Bs[srow * 40 + scol]) = b0;
        *(uint4*)(&Bs[(srow + 64) * 40 + scol]) = b1;
        __syncthreads();

        bf16x8 af[4], bfr[4];
#pragma unroll
        for (int i = 0; i < 4; i++)
            af[i] = *(const bf16x8*)(&As[(wm + i * 16 + l16) * 40 + quad * 8]);
#pragma unroll
        for (int j = 0; j < 4; j++)
            bfr[j] = *(const bf16x8*)(&Bs[(wn + j * 16 + l16) * 40 + quad * 8]);
#pragma unroll
        for (int i = 0; i < 4; i++)
#pragma unroll
            for (int j = 0; j < 4; j++)
                acc[i][j] = MFMA16(af[i], bfr[j], acc[i][j]);
        __syncthreads();
    }

    // D layout: col = lane&15, row = quad*4 + reg  [measured: learn_hip m89/m91]
#pragma unroll
    for (int i = 0; i < 4; i++)
#pragma unroll
        for (int j = 0; j < 4; j++)
#pragma unroll
            for (int r = 0; r < 4; r++) {
                int row = bm + wm + i * 16 + quad * 4 + r;
                int col = bn + wn + j * 16 + l16;
                store_out(C + (size_t)row * N + col, acc[i][j][r]);
            }
}

// ---------------------------------------------------------------- flash attention
// grid: (32 q-tiles of 64 rows, 32 heads). 4 waves; wave w owns q-rows w*16..w*16+15.
// Q pre-scaled by 1/sqrt(128) in rope. GQA: head h uses kv head h>>2.
__global__ __launch_bounds__(256) void flash_attn(const ushort_t* __restrict__ Q,
                                                  const ushort_t* __restrict__ Kp,
                                                  const ushort_t* __restrict__ Vp,
                                                  ushort_t* __restrict__ Y) {
    const int qt = blockIdx.x, h = blockIdx.y, kh = h >> 2;
    const int tid = threadIdx.x;
    const int w = tid >> 6, lane = tid & 63;
    const int quad = lane >> 4, l16 = lane & 15;

    __shared__ ushort_t Ks[64 * 136];     // 64 keys x 128 dims, pad 136
    __shared__ ushort_t Vt[128 * 72];     // transposed: Vt[c*72 + k] = V[k][c]
    __shared__ ushort_t Ps[4 * 16 * 72];  // per-wave P round-trip (D->A layout)

    // Preload Q fragments (A-operand: m = lane&15, k = quad*8+j), 4 k-steps of 32
    bf16x8 qf[4];
    {
        const ushort_t* qrow = Q + (size_t)(qt * 64 + w * 16 + l16) * 4096 + h * 128 + quad * 8;
#pragma unroll
        for (int ks = 0; ks < 4; ks++) qf[ks] = *(const bf16x8*)(qrow + ks * 32);
    }

    f32x4 o[8] = {};
    float m_i[4], l_i[4];
#pragma unroll
    for (int r = 0; r < 4; r++) { m_i[r] = -1e30f; l_i[r] = 0.f; }

    const int ntiles = qt + 1;  // causal: only tiles with keys <= last q row
    for (int j = 0; j < ntiles; j++) {
        const int t0 = j * 64;
        // stage K tile (row-major) — 16B vector loads
        {
            int r = tid >> 4, c = (tid & 15) * 8;
#pragma unroll
            for (int p = 0; p < 4; p++) {
                uint4 d = *(const uint4*)(Kp + (size_t)(t0 + p * 16 + r) * 1024 + kh * 128 + c);
                *(uint4*)(&Ks[(p * 16 + r) * 136 + c]) = d;
            }
        }
        // stage V transposed
        {
            int k = tid >> 4, c0 = (tid & 15) * 8;
#pragma unroll
            for (int p = 0; p < 4; p++) {
                int kk = p * 16 + k;
                uint4 d = *(const uint4*)(Vp + (size_t)(t0 + kk) * 1024 + kh * 128 + c0);
                const ushort_t* ds = (const ushort_t*)&d;
#pragma unroll
                for (int e = 0; e < 8; e++) Vt[(c0 + e) * 72 + kk] = ds[e];
            }
        }
        __syncthreads();

        // S = Q_tile @ K_tile^T : 4 column-tiles x 4 k-steps
        f32x4 s[4] = {};
#pragma unroll
        for (int ct = 0; ct < 4; ct++)
#pragma unroll
            for (int ks = 0; ks < 4; ks++) {
                bf16x8 kf = *(const bf16x8*)(&Ks[(ct * 16 + l16) * 136 + ks * 32 + quad * 8]);
                s[ct] = MFMA16(qf[ks], kf, s[ct]);
            }

        // causal mask (only diagonal tile has masked entries)
        if (j == qt) {
#pragma unroll
            for (int ct = 0; ct < 4; ct++)
#pragma unroll
                for (int r = 0; r < 4; r++) {
                    int rg = w * 16 + quad * 4 + r;
                    int cg = ct * 16 + l16;
                    if (cg > rg) s[ct][r] = -1e30f;
                }
        }

        // online softmax — each quad-group of 16 lanes shares rows quad*4+r
        float alpha[4];
#pragma unroll
        for (int r = 0; r < 4; r++) {
            float v = fmaxf(fmaxf(s[0][r], s[1][r]), fmaxf(s[2][r], s[3][r]));
            v = fmaxf(v, __shfl_xor(v, 1));
            v = fmaxf(v, __shfl_xor(v, 2));
            v = fmaxf(v, __shfl_xor(v, 4));
            v = fmaxf(v, __shfl_xor(v, 8));
            float mn = fmaxf(m_i[r], v);
            alpha[r] = __expf(m_i[r] - mn);
            m_i[r] = mn;
        }
        float rs[4] = {0.f, 0.f, 0.f, 0.f};
#pragma unroll
        for (int ct = 0; ct < 4; ct++)
#pragma unroll
            for (int r = 0; r < 4; r++) {
                float p = __expf(s[ct][r] - m_i[r]);
                s[ct][r] = p;
                rs[r] += p;
            }
#pragma unroll
        for (int r = 0; r < 4; r++) {
            float v = rs[r];
            v += __shfl_xor(v, 1);
            v += __shfl_xor(v, 2);
            v += __shfl_xor(v, 4);
            v += __shfl_xor(v, 8);
            l_i[r] = alpha[r] * l_i[r] + v;
        }
#pragma unroll
        for (int n = 0; n < 8; n++)
#pragma unroll
            for (int r = 0; r < 4; r++) o[n][r] *= alpha[r];

        // P: D-layout -> A-layout via per-wave LDS region
#pragma unroll
        for (int ct = 0; ct < 4; ct++)
#pragma unroll
            for (int r = 0; r < 4; r++)
                Ps[w * 16 * 72 + (quad * 4 + r) * 72 + ct * 16 + l16] = f2bf(s[ct][r]);
        __syncthreads();

        // O += P (16x64) @ V (64x128): 2 k-steps x 8 n-tiles
#pragma unroll
        for (int ks2 = 0; ks2 < 2; ks2++) {
            bf16x8 pf = *(const bf16x8*)(&Ps[w * 16 * 72 + l16 * 72 + ks2 * 32 + quad * 8]);
#pragma unroll
            for (int n = 0; n < 8; n++) {
                bf16x8 vf = *(const bf16x8*)(&Vt[(n * 16 + l16) * 72 + ks2 * 32 + quad * 8]);
                o[n] = MFMA16(pf, vf, o[n]);
            }
        }
        __syncthreads();
    }

    // normalize + store y (bf16, layout (T, 4096))
    float inv[4];
#pragma unroll
    for (int r = 0; r < 4; r++) inv[r] = 1.0f / l_i[r];
#pragma unroll
    for (int n = 0; n < 8; n++)
#pragma unroll
        for (int r = 0; r < 4; r++) {
            int row = qt * 64 + w * 16 + quad * 4 + r;
            int col = h * 128 + n * 16 + l16;
            Y[(size_t)row * 4096 + col] = f2bf(o[n][r] * inv[r]);
        }
}

// ---------------------------------------------------------------- launch
extern "C" void kernel_launch(void* const* d_in, const int* in_sizes, int n_in,
                              void* d_out, int out_size, void* d_ws, size_t ws_size,
                              hipStream_t stream) {
    const float* x    = (const float*)d_in[0];
    const float* cosp = (const float*)d_in[1];
    const float* sinp = (const float*)d_in[2];
    const float* wq   = (const float*)d_in[3];
    const float* wk   = (const float*)d_in[4];
    const float* wv   = (const float*)d_in[5];
    const float* wo   = (const float*)d_in[6];
    float* out = (float*)d_out;

    // workspace layout (bf16 elements), ~109 MB total
    ushort_t* xb   = (ushort_t*)d_ws;
    ushort_t* qb   = xb  + (size_t)2048 * 4096;
    ushort_t* yb   = qb  + (size_t)2048 * 4096;
    ushort_t* kb   = yb  + (size_t)2048 * 4096;
    ushort_t* vb   = kb  + (size_t)2048 * 1024;
    ushort_t* wkb  = vb  + (size_t)2048 * 1024;
    ushort_t* wvb  = wkb + (size_t)1024 * 4096;
    ushort_t* wbig = wvb + (size_t)1024 * 4096;  // wq, then reused for wo

    // casts
    cast_f32_bf16<<<(2048 * 4096 / 4 + 255) / 256, 256, 0, stream>>>(x, xb, 2048 * 4096 / 4);
    cast_f32_bf16<<<(4096 * 4096 / 4 + 255) / 256, 256, 0, stream>>>(wq, wbig, 4096 * 4096 / 4);
    cast_f32_bf16<<<(1024 * 4096 / 4 + 255) / 256, 256, 0, stream>>>(wk, wkb, 1024 * 4096 / 4);
    cast_f32_bf16<<<(1024 * 4096 / 4 + 255) / 256, 256, 0, stream>>>(wv, wvb, 1024 * 4096 / 4);

    // Q projection: (2048,4096) = xb @ wq^T
    {
        dim3 g(2048 / 128, 4096 / 128, 1);
        gemm_bt<ushort_t><<<g, 256, 0, stream>>>(xb, wbig, wbig, qb, qb, 2048, 4096, 4096);
    }
    // K and V projections fused over grid.z
    {
        dim3 g(2048 / 128, 1024 / 128, 2);
        gemm_bt<ushort_t><<<g, 256, 0, stream>>>(xb, wkb, wvb, kb, vb, 2048, 1024, 4096);
    }
    // RoPE (q fused with softmax scale)
    const float scale = 0.08838834764831845f;  // 1/sqrt(128)
    rope_kernel<<<(2048 * 2048 + 255) / 256, 256, 0, stream>>>(qb, cosp, sinp, 2048, scale, 2048 * 2048);
    rope_kernel<<<(2048 * 512 + 255) / 256, 256, 0, stream>>>(kb, cosp, sinp, 512, 1.0f, 2048 * 512);

    // flash attention
    {
        dim3 g(32, 32, 1);
        flash_attn<<<g, 256, 0, stream>>>(qb, kb, vb, yb);
    }

    // output projection: out = y @ wo^T (fp32 out)
    cast_f32_bf16<<<(4096 * 4096 / 4 + 255) / 256, 256, 0, stream>>>(wo, wbig, 4096 * 4096 / 4);
    {
        dim3 g(2048 / 128, 4096 / 128, 1);
        gemm_bt<float><<<g, 256, 0, stream>>>(yb, wbig, wbig, out, out, 2048, 4096, 4096);
    }
}

// Round 2
// 616.227 us; speedup vs baseline: 1.4812x; 1.4812x over previous
//
#include <hip/hip_runtime.h>
#include <stdint.h>

typedef unsigned short ushort_t;
typedef __bf16 bf16_t;
typedef __attribute__((ext_vector_type(8))) __bf16 bf16x8;
typedef __attribute__((ext_vector_type(4))) float f32x4;

#define MFMA16(a, b, c) __builtin_amdgcn_mfma_f32_16x16x32_bf16((a), (b), (c), 0, 0, 0)

__device__ __forceinline__ ushort_t f2bf(float f) {
    unsigned u = __float_as_uint(f);
    u += 0x7fffu + ((u >> 16) & 1u);   // round-to-nearest-even
    return (ushort_t)(u >> 16);
}
__device__ __forceinline__ float bf2f(ushort_t h) {
    return __uint_as_float(((unsigned)h) << 16);
}

// async global->LDS 16B (m97 path). LDS dest is wave-uniform base + lane*16:
// caller must ensure per-lane lds offsets are (uniform + lane*16).
typedef __attribute__((address_space(1))) const unsigned char g_u8;
typedef __attribute__((address_space(3))) unsigned char l_u8;
__device__ __forceinline__ void gload16(const void* g, void* l) {
    __builtin_amdgcn_global_load_lds((g_u8*)g, (l_u8*)(unsigned int)(uintptr_t)l, 16, 0, 0);
}

// ---------------------------------------------------------------- cast f32 -> bf16
__global__ __launch_bounds__(256) void cast_f32_bf16(const float* __restrict__ in,
                                                     ushort_t* __restrict__ out, int n4) {
    int i = blockIdx.x * 256 + threadIdx.x;
    if (i < n4) {
        float4 v = ((const float4*)in)[i];
        ushort4 o;
        o.x = f2bf(v.x); o.y = f2bf(v.y); o.z = f2bf(v.z); o.w = f2bf(v.w);
        ((ushort4*)out)[i] = o;
    }
}

// ---------------------------------------------------------------- RoPE (in-place, bf16)
__global__ __launch_bounds__(256) void rope_kernel(ushort_t* __restrict__ X,
                                                   const float* __restrict__ cs,
                                                   const float* __restrict__ sn,
                                                   int ppr, float scale, int total) {
    int idx = blockIdx.x * 256 + threadIdx.x;
    if (idx >= total) return;
    int t = idx / ppr;
    int p = idx - t * ppr;
    int h = p >> 6, j = p & 63;
    int c0 = h * 128 + j * 2;
    ushort_t* row = X + (size_t)t * (ppr * 2);
    float x1 = bf2f(row[c0]), x2 = bf2f(row[c0 + 1]);
    float c = cs[t * 64 + j], s = sn[t * 64 + j];
    row[c0]     = f2bf((x1 * c - x2 * s) * scale);
    row[c0 + 1] = f2bf((x1 * s + x2 * c) * scale);
}

// ---------------------------------------------------------------- bf16 transpose (in R x C -> out C x R)
__global__ __launch_bounds__(256) void transpose_bf16(const ushort_t* __restrict__ in,
                                                      ushort_t* __restrict__ out,
                                                      int R, int C) {
    __shared__ __align__(16) ushort_t t[64][80];   // stride 80: rows 160B, 16B-aligned
    const int r0 = blockIdx.x * 64, c0 = blockIdx.y * 64;
    const int tid = threadIdx.x;
    const int lr = tid >> 3, lc = (tid & 7) * 8;
#pragma unroll
    for (int p = 0; p < 2; p++) {
        uint4 d = *(const uint4*)(in + (size_t)(r0 + lr + p * 32) * C + c0 + lc);
        *(uint4*)(&t[lr + p * 32][lc]) = d;
    }
    __syncthreads();
#pragma unroll
    for (int p = 0; p < 2; p++) {
        int orow = lr + p * 32;                   // out row = in col c0+orow
        ushort_t tmp[8];
#pragma unroll
        for (int e = 0; e < 8; e++) tmp[e] = t[lc + e][orow];
        *(uint4*)(out + (size_t)(c0 + orow) * R + r0 + lc) = *(uint4*)tmp;
    }
}

// ---------------------------------------------------------------- GEMM: C = A @ B^T (m97 structure)
// A (M,K) bf16 rm, B (N,K) bf16 rm. 128x128 tile, BK=32, 4 waves, global_load_lds staging.
__device__ __forceinline__ void store_out(ushort_t* p, float v) { *p = f2bf(v); }
__device__ __forceinline__ void store_out(float* p, float v) { *p = v; }

template <typename OutT>
__global__ __launch_bounds__(256) void gemm_bt(const ushort_t* __restrict__ A,
                                               const ushort_t* __restrict__ B0,
                                               const ushort_t* __restrict__ B1,
                                               OutT* __restrict__ C0, OutT* __restrict__ C1,
                                               int M, int N, int K) {
    const ushort_t* B = (blockIdx.z == 0) ? B0 : B1;
    OutT* C = (blockIdx.z == 0) ? C0 : C1;
    const int bm = blockIdx.x * 128, bn = blockIdx.y * 128;
    // UNPADDED stride-32: required so staging LDS offsets are tid*16B
    // (wave-uniform + lane*16 — global_load_lds constraint, m104/m108).
    __shared__ __align__(16) ushort_t As[128 * 32];
    __shared__ __align__(16) ushort_t Bs[128 * 32];
    const int tid = threadIdx.x;
    const int w = tid >> 6, lane = tid & 63;
    const int quad = lane >> 4, l16 = lane & 15;
    const int wm = (w >> 1) * 64, wn = (w & 1) * 64;
    f32x4 acc[4][4] = {};

    const int srow = tid >> 2;          // 0..63
    const int scol = (tid & 3) * 8;     // 16B chunk within the 32-elem row
    const ushort_t* Ag = A + (size_t)(bm + srow) * K + scol;
    const ushort_t* Bg = B + (size_t)(bn + srow) * K + scol;

    for (int k0 = 0; k0 < K; k0 += 32) {
        // element offset tid*8 == (srow*32 + scol)  => lane-contiguous 16B chunks
        gload16(Ag + k0,                  As + tid * 8);
        gload16(Ag + (size_t)64 * K + k0, As + 2048 + tid * 8);
        gload16(Bg + k0,                  Bs + tid * 8);
        gload16(Bg + (size_t)64 * K + k0, Bs + 2048 + tid * 8);
        __syncthreads();   // compiler emits vmcnt(0) drain before s_barrier

        bf16x8 af[4], bfr[4];
#pragma unroll
        for (int i = 0; i < 4; i++)
            af[i] = *(const bf16x8*)(&As[(wm + i * 16 + l16) * 32 + quad * 8]);
#pragma unroll
        for (int j = 0; j < 4; j++)
            bfr[j] = *(const bf16x8*)(&Bs[(wn + j * 16 + l16) * 32 + quad * 8]);
#pragma unroll
        for (int i = 0; i < 4; i++)
#pragma unroll
            for (int j = 0; j < 4; j++)
                acc[i][j] = MFMA16(af[i], bfr[j], acc[i][j]);
        __syncthreads();
    }

    // D layout: col = lane&15, row = quad*4 + reg  [m89/m91]
#pragma unroll
    for (int i = 0; i < 4; i++)
#pragma unroll
        for (int j = 0; j < 4; j++)
#pragma unroll
            for (int r = 0; r < 4; r++) {
                int row = bm + wm + i * 16 + quad * 4 + r;
                int col = bn + wn + j * 16 + l16;
                store_out(C + (size_t)row * N + col, acc[i][j][r]);
            }
}

// ---------------------------------------------------------------- flash attention
// grid (16, 32): block handles q-tiles qt=bx and qt=31-bx => uniform 33 tile-iters.
// 4 waves; wave w owns q-rows w*16..w*16+15 of the 64-row tile.
// Q pre-scaled by 1/sqrt(128). GQA: head h uses kv head h>>2. V passed TRANSPOSED (128h*... dims x 2048 keys... rows=dim).
__global__ __launch_bounds__(256) void flash_attn(const ushort_t* __restrict__ Q,
                                                  const ushort_t* __restrict__ Kp,
                                                  const ushort_t* __restrict__ Vt,   // (1024, 2048): Vt[d][t]
                                                  ushort_t* __restrict__ Y) {
    const int h = blockIdx.y, kh = h >> 2;
    const int tid = threadIdx.x;
    const int w = tid >> 6, lane = tid & 63;
    const int quad = lane >> 4, l16 = lane & 15;

    __shared__ __align__(16) ushort_t Ks[64 * 136];    // keys x dims, 272B rows (16B-aligned)
    __shared__ __align__(16) ushort_t VtS[128 * 80];   // dims x keys, 160B rows
    __shared__ __align__(16) ushort_t Ps[4 * 16 * 80]; // per-wave P (D->A layout round-trip)

#pragma unroll 1
    for (int phase = 0; phase < 2; phase++) {
        const int qt = (phase == 0) ? blockIdx.x : 31 - blockIdx.x;

        // Q fragments (A-operand: m=lane&15, k=quad*8+j), 4 k-steps of 32
        bf16x8 qf[4];
        {
            const ushort_t* qrow = Q + (size_t)(qt * 64 + w * 16 + l16) * 4096 + h * 128 + quad * 8;
#pragma unroll
            for (int ks = 0; ks < 4; ks++) qf[ks] = *(const bf16x8*)(qrow + ks * 32);
        }

        f32x4 o[8] = {};
        float m_i[4], l_i[4];
#pragma unroll
        for (int r = 0; r < 4; r++) { m_i[r] = -1e30f; l_i[r] = 0.f; }

        const int ntiles = qt + 1;
        for (int j = 0; j < ntiles; j++) {
            const int t0 = j * 64;
            // stage K tile: 64 rows x 128 dims, 16 chunks/row, 4 chunks/thread
            {
#pragma unroll
                for (int p = 0; p < 4; p++) {
                    int ck = p * 256 + tid;
                    int r = ck >> 4, c = (ck & 15) * 8;
                    uint4 d = *(const uint4*)(Kp + (size_t)(t0 + r) * 1024 + kh * 128 + c);
                    *(uint4*)(&Ks[r * 136 + c]) = d;
                }
            }
            // stage V^T tile from global Vt: 128 dim-rows x 64 keys, 8 chunks/row
            {
#pragma unroll
                for (int p = 0; p < 4; p++) {
                    int ck = p * 256 + tid;
                    int d = ck >> 3, c = (ck & 7) * 8;
                    uint4 v = *(const uint4*)(Vt + (size_t)(kh * 128 + d) * 2048 + t0 + c);
                    *(uint4*)(&VtS[d * 80 + c]) = v;
                }
            }
            __syncthreads();

            // S = Q @ K^T : 4 col-tiles x 4 k-steps
            f32x4 s[4] = {};
#pragma unroll
            for (int ct = 0; ct < 4; ct++)
#pragma unroll
                for (int ks = 0; ks < 4; ks++) {
                    bf16x8 kf = *(const bf16x8*)(&Ks[(ct * 16 + l16) * 136 + ks * 32 + quad * 8]);
                    s[ct] = MFMA16(qf[ks], kf, s[ct]);
                }

            if (j == qt) {   // diagonal tile: causal mask
#pragma unroll
                for (int ct = 0; ct < 4; ct++)
#pragma unroll
                    for (int r = 0; r < 4; r++) {
                        int rg = w * 16 + quad * 4 + r;
                        int cg = ct * 16 + l16;
                        if (cg > rg) s[ct][r] = -1e30f;
                    }
            }

            // online softmax (16 lanes of each quad share rows quad*4+r)
            float alpha[4];
#pragma unroll
            for (int r = 0; r < 4; r++) {
                float v = fmaxf(fmaxf(s[0][r], s[1][r]), fmaxf(s[2][r], s[3][r]));
                v = fmaxf(v, __shfl_xor(v, 1));
                v = fmaxf(v, __shfl_xor(v, 2));
                v = fmaxf(v, __shfl_xor(v, 4));
                v = fmaxf(v, __shfl_xor(v, 8));
                float mn = fmaxf(m_i[r], v);
                alpha[r] = __expf(m_i[r] - mn);
                m_i[r] = mn;
            }
            float rs[4] = {0.f, 0.f, 0.f, 0.f};
#pragma unroll
            for (int ct = 0; ct < 4; ct++)
#pragma unroll
                for (int r = 0; r < 4; r++) {
                    float p = __expf(s[ct][r] - m_i[r]);
                    s[ct][r] = p;
                    rs[r] += p;
                }
#pragma unroll
            for (int r = 0; r < 4; r++) {
                float v = rs[r];
                v += __shfl_xor(v, 1);
                v += __shfl_xor(v, 2);
                v += __shfl_xor(v, 4);
                v += __shfl_xor(v, 8);
                l_i[r] = alpha[r] * l_i[r] + v;
            }
#pragma unroll
            for (int n = 0; n < 8; n++)
#pragma unroll
                for (int r = 0; r < 4; r++) o[n][r] *= alpha[r];

            // P: D-layout -> A-layout via per-wave LDS region
#pragma unroll
            for (int ct = 0; ct < 4; ct++)
#pragma unroll
                for (int r = 0; r < 4; r++)
                    Ps[w * 16 * 80 + (quad * 4 + r) * 80 + ct * 16 + l16] = f2bf(s[ct][r]);
            __syncthreads();

            // O += P (16x64) @ V (64x128)
#pragma unroll
            for (int ks2 = 0; ks2 < 2; ks2++) {
                bf16x8 pf = *(const bf16x8*)(&Ps[w * 16 * 80 + l16 * 80 + ks2 * 32 + quad * 8]);
#pragma unroll
                for (int n = 0; n < 8; n++) {
                    bf16x8 vf = *(const bf16x8*)(&VtS[(n * 16 + l16) * 80 + ks2 * 32 + quad * 8]);
                    o[n] = MFMA16(pf, vf, o[n]);
                }
            }
            __syncthreads();
        }

        float inv[4];
#pragma unroll
        for (int r = 0; r < 4; r++) inv[r] = 1.0f / l_i[r];
#pragma unroll
        for (int n = 0; n < 8; n++)
#pragma unroll
            for (int r = 0; r < 4; r++) {
                int row = qt * 64 + w * 16 + quad * 4 + r;
                int col = h * 128 + n * 16 + l16;
                Y[(size_t)row * 4096 + col] = f2bf(o[n][r] * inv[r]);
            }
    }
}

// ---------------------------------------------------------------- launch
extern "C" void kernel_launch(void* const* d_in, const int* in_sizes, int n_in,
                              void* d_out, int out_size, void* d_ws, size_t ws_size,
                              hipStream_t stream) {
    const float* x    = (const float*)d_in[0];
    const float* cosp = (const float*)d_in[1];
    const float* sinp = (const float*)d_in[2];
    const float* wq   = (const float*)d_in[3];
    const float* wk   = (const float*)d_in[4];
    const float* wv   = (const float*)d_in[5];
    const float* wo   = (const float*)d_in[6];
    float* out = (float*)d_out;

    // workspace layout (bf16 elements), ~104 MB
    ushort_t* xb   = (ushort_t*)d_ws;
    ushort_t* qb   = xb  + (size_t)2048 * 4096;
    ushort_t* yb   = qb  + (size_t)2048 * 4096;
    ushort_t* kb   = yb  + (size_t)2048 * 4096;
    ushort_t* vb   = kb  + (size_t)2048 * 1024;
    ushort_t* wkb  = vb  + (size_t)2048 * 1024;
    ushort_t* wvb  = wkb + (size_t)1024 * 4096;
    ushort_t* wbig = wvb + (size_t)1024 * 4096;  // 16M elems: wq, then vt overlay, then wo
    // vt (1024x2048 = 2M elems) overlays the first 4MB of wbig AFTER the Q-gemm
    // consumed wq and BEFORE the wo cast rewrites wbig (stream-serial => safe).
    ushort_t* vtb  = wbig;

    cast_f32_bf16<<<(2048 * 4096 / 4 + 255) / 256, 256, 0, stream>>>(x, xb, 2048 * 4096 / 4);
    cast_f32_bf16<<<(4096 * 4096 / 4 + 255) / 256, 256, 0, stream>>>(wq, wbig, 4096 * 4096 / 4);
    cast_f32_bf16<<<(1024 * 4096 / 4 + 255) / 256, 256, 0, stream>>>(wk, wkb, 1024 * 4096 / 4);
    cast_f32_bf16<<<(1024 * 4096 / 4 + 255) / 256, 256, 0, stream>>>(wv, wvb, 1024 * 4096 / 4);

    {   // Q projection (2048,4096) = xb @ wq^T
        dim3 g(2048 / 128, 4096 / 128, 1);
        gemm_bt<ushort_t><<<g, 256, 0, stream>>>(xb, wbig, wbig, qb, qb, 2048, 4096, 4096);
    }
    {   // K and V projections fused over grid.z
        dim3 g(2048 / 128, 1024 / 128, 2);
        gemm_bt<ushort_t><<<g, 256, 0, stream>>>(xb, wkb, wvb, kb, vb, 2048, 1024, 4096);
    }
    // V -> V^T (overlays wbig; wq already consumed)
    transpose_bf16<<<dim3(2048 / 64, 1024 / 64), 256, 0, stream>>>(vb, vtb, 2048, 1024);

    const float scale = 0.08838834764831845f;  // 1/sqrt(128), fused into q rope
    rope_kernel<<<(2048 * 2048 + 255) / 256, 256, 0, stream>>>(qb, cosp, sinp, 2048, scale, 2048 * 2048);
    rope_kernel<<<(2048 * 512 + 255) / 256, 256, 0, stream>>>(kb, cosp, sinp, 512, 1.0f, 2048 * 512);

    {   // flash attention (paired-causal blocks)
        dim3 g(16, 32, 1);
        flash_attn<<<g, 256, 0, stream>>>(qb, kb, vtb, yb);
    }

    // wo cast (overwrites the vt overlay — flash already done) + output projection
    cast_f32_bf16<<<(4096 * 4096 / 4 + 255) / 256, 256, 0, stream>>>(wo, wbig, 4096 * 4096 / 4);
    {
        dim3 g(2048 / 128, 4096 / 128, 1);
        gemm_bt<float><<<g, 256, 0, stream>>>(yb, wbig, wbig, out, out, 2048, 4096, 4096);
    }
}

// Round 3
// 589.128 us; speedup vs baseline: 1.5494x; 1.0460x over previous
//
#include <hip/hip_runtime.h>
#include <stdint.h>

typedef unsigned short ushort_t;
typedef __attribute__((ext_vector_type(8))) __bf16 bf16x8;
typedef __attribute__((ext_vector_type(4))) float f32x4;

#define MFMA16(a, b, c) __builtin_amdgcn_mfma_f32_16x16x32_bf16((a), (b), (c), 0, 0, 0)

__device__ __forceinline__ ushort_t f2bf(float f) {
    unsigned u = __float_as_uint(f);
    u += 0x7fffu + ((u >> 16) & 1u);   // round-to-nearest-even
    return (ushort_t)(u >> 16);
}

// async global->LDS 16B (m97 path). LDS dest must be wave-uniform base + lane*16.
typedef __attribute__((address_space(1))) const unsigned char g_u8;
typedef __attribute__((address_space(3))) unsigned char l_u8;
__device__ __forceinline__ void gload16(const void* g, void* l) {
    __builtin_amdgcn_global_load_lds((g_u8*)g, (l_u8*)(unsigned int)(uintptr_t)l, 16, 0, 0);
}

// ---------------------------------------------------------------- fused casts f32 -> bf16
// x (8M elems), wq (16M), wk (4M), wv (4M) in one launch; indices in float4 groups.
__global__ __launch_bounds__(256) void cast_multi(const float* __restrict__ x,
                                                  const float* __restrict__ wq,
                                                  const float* __restrict__ wk,
                                                  const float* __restrict__ wv,
                                                  ushort_t* __restrict__ xb,
                                                  ushort_t* __restrict__ wqb,
                                                  ushort_t* __restrict__ wkb,
                                                  ushort_t* __restrict__ wvb) {
    int i = blockIdx.x * 256 + threadIdx.x;
    const float* in; ushort_t* out; int off;
    if (i < 2097152)      { in = x;  out = xb;  off = i; }
    else if (i < 6291456) { in = wq; out = wqb; off = i - 2097152; }
    else if (i < 7340032) { in = wk; out = wkb; off = i - 6291456; }
    else                  { in = wv; out = wvb; off = i - 7340032; }
    float4 v = ((const float4*)in)[off];
    ushort4 o;
    o.x = f2bf(v.x); o.y = f2bf(v.y); o.z = f2bf(v.z); o.w = f2bf(v.w);
    ((ushort4*)out)[off] = o;
}

__global__ __launch_bounds__(256) void cast_f32_bf16(const float* __restrict__ in,
                                                     ushort_t* __restrict__ out, int n4) {
    int i = blockIdx.x * 256 + threadIdx.x;
    if (i < n4) {
        float4 v = ((const float4*)in)[i];
        ushort4 o;
        o.x = f2bf(v.x); o.y = f2bf(v.y); o.z = f2bf(v.z); o.w = f2bf(v.w);
        ((ushort4*)out)[i] = o;
    }
}

// ---------------------------------------------------------------- fused QKV GEMM
// A (2048,4096) bf16. by<32: Q=A@wq^T (+rope, *1/sqrt(128)) -> qb (2048,4096)
//                    by<40: K=A@wk^T (+rope)                -> kb (2048,1024)
//                    else : V=A@wv^T, stored TRANSPOSED     -> vt (1024,2048)
// m97 structure: 128x128 tile, BK=32, global_load_lds width-16 staging.
__global__ __launch_bounds__(256) void gemm_qkv(const ushort_t* __restrict__ A,
                                                const ushort_t* __restrict__ Wq,
                                                const ushort_t* __restrict__ Wk,
                                                const ushort_t* __restrict__ Wv,
                                                ushort_t* __restrict__ Qo,
                                                ushort_t* __restrict__ Ko,
                                                ushort_t* __restrict__ VtO,
                                                const float* __restrict__ cosp,
                                                const float* __restrict__ sinp) {
    const int by = blockIdx.y;
    const ushort_t* B;
    int region, bn;
    if (by < 32)      { region = 0; B = Wq; bn = by * 128; }
    else if (by < 40) { region = 1; B = Wk; bn = (by - 32) * 128; }
    else              { region = 2; B = Wv; bn = (by - 40) * 128; }
    const int bm = blockIdx.x * 128;

    __shared__ __align__(16) ushort_t As[128 * 32];  // unpadded: global_load_lds needs tid*16B
    __shared__ __align__(16) ushort_t Bs[128 * 32];
    const int tid = threadIdx.x;
    const int w = tid >> 6, lane = tid & 63;
    const int quad = lane >> 4, l16 = lane & 15;
    const int wm = (w >> 1) * 64, wn = (w & 1) * 64;
    f32x4 acc[4][4] = {};

    const int srow = tid >> 2;
    const int scol = (tid & 3) * 8;
    const ushort_t* Ag = A + (size_t)(bm + srow) * 4096 + scol;
    const ushort_t* Bg = B + (size_t)(bn + srow) * 4096 + scol;

    for (int k0 = 0; k0 < 4096; k0 += 32) {
        gload16(Ag + k0,                 As + tid * 8);
        gload16(Ag + (size_t)64 * 4096 + k0, As + 2048 + tid * 8);
        gload16(Bg + k0,                 Bs + tid * 8);
        gload16(Bg + (size_t)64 * 4096 + k0, Bs + 2048 + tid * 8);
        __syncthreads();

        bf16x8 af[4], bfr[4];
#pragma unroll
        for (int i = 0; i < 4; i++)
            af[i] = *(const bf16x8*)(&As[(wm + i * 16 + l16) * 32 + quad * 8]);
#pragma unroll
        for (int j = 0; j < 4; j++)
            bfr[j] = *(const bf16x8*)(&Bs[(wn + j * 16 + l16) * 32 + quad * 8]);
#pragma unroll
        for (int i = 0; i < 4; i++)
#pragma unroll
            for (int j = 0; j < 4; j++)
                acc[i][j] = MFMA16(af[i], bfr[j], acc[i][j]);
        __syncthreads();
    }

    // epilogue. D layout: col = lane&15, row = quad*4+reg [m89/m91]
    const float qscale = 0.08838834764831845f;  // 1/sqrt(128)
    if (region < 2) {
        ushort_t* C = (region == 0) ? Qo : Ko;
        const int Nc = (region == 0) ? 4096 : 1024;
        const float scl = (region == 0) ? qscale : 1.0f;
#pragma unroll
        for (int i = 0; i < 4; i++)
#pragma unroll
            for (int j = 0; j < 4; j++) {
                const int col = bn + wn + j * 16 + l16;
                const int pj = (col & 127) >> 1;
#pragma unroll
                for (int r = 0; r < 4; r++) {
                    const int row = bm + wm + i * 16 + quad * 4 + r;
                    float v = acc[i][j][r];
                    float p = __shfl_xor(v, 1);         // partner column (col^1)
                    float c = cosp[row * 64 + pj], s = sinp[row * 64 + pj];
                    float res = (col & 1) ? fmaf(p, s, v * c)   // odd: x1*s + x2*c
                                          : (v * c - p * s);    // even: x1*c - x2*s
                    C[(size_t)row * Nc + col] = f2bf(res * scl);
                }
            }
    } else {
        // V^T: VtO[dim][token], reg r spans 4 consecutive tokens -> 8B packed store
#pragma unroll
        for (int i = 0; i < 4; i++) {
            const int rowb = bm + wm + i * 16 + quad * 4;   // token base
#pragma unroll
            for (int j = 0; j < 4; j++) {
                const int col = bn + wn + j * 16 + l16;     // dim
                ushort4 pk;
                pk.x = f2bf(acc[i][j][0]); pk.y = f2bf(acc[i][j][1]);
                pk.z = f2bf(acc[i][j][2]); pk.w = f2bf(acc[i][j][3]);
                *(ushort4*)(VtO + (size_t)col * 2048 + rowb) = pk;
            }
        }
    }
}

// ---------------------------------------------------------------- GEMM: C = A @ B^T (wo)
__global__ __launch_bounds__(256) void gemm_bt(const ushort_t* __restrict__ A,
                                               const ushort_t* __restrict__ B,
                                               float* __restrict__ C,
                                               int M, int N, int K) {
    const int bm = blockIdx.x * 128, bn = blockIdx.y * 128;
    __shared__ __align__(16) ushort_t As[128 * 32];
    __shared__ __align__(16) ushort_t Bs[128 * 32];
    const int tid = threadIdx.x;
    const int w = tid >> 6, lane = tid & 63;
    const int quad = lane >> 4, l16 = lane & 15;
    const int wm = (w >> 1) * 64, wn = (w & 1) * 64;
    f32x4 acc[4][4] = {};

    const int srow = tid >> 2;
    const int scol = (tid & 3) * 8;
    const ushort_t* Ag = A + (size_t)(bm + srow) * K + scol;
    const ushort_t* Bg = B + (size_t)(bn + srow) * K + scol;

    for (int k0 = 0; k0 < K; k0 += 32) {
        gload16(Ag + k0,                  As + tid * 8);
        gload16(Ag + (size_t)64 * K + k0, As + 2048 + tid * 8);
        gload16(Bg + k0,                  Bs + tid * 8);
        gload16(Bg + (size_t)64 * K + k0, Bs + 2048 + tid * 8);
        __syncthreads();

        bf16x8 af[4], bfr[4];
#pragma unroll
        for (int i = 0; i < 4; i++)
            af[i] = *(const bf16x8*)(&As[(wm + i * 16 + l16) * 32 + quad * 8]);
#pragma unroll
        for (int j = 0; j < 4; j++)
            bfr[j] = *(const bf16x8*)(&Bs[(wn + j * 16 + l16) * 32 + quad * 8]);
#pragma unroll
        for (int i = 0; i < 4; i++)
#pragma unroll
            for (int j = 0; j < 4; j++)
                acc[i][j] = MFMA16(af[i], bfr[j], acc[i][j]);
        __syncthreads();
    }

#pragma unroll
    for (int i = 0; i < 4; i++)
#pragma unroll
        for (int j = 0; j < 4; j++)
#pragma unroll
            for (int r = 0; r < 4; r++) {
                int row = bm + wm + i * 16 + quad * 4 + r;
                int col = bn + wn + j * 16 + l16;
                C[(size_t)row * N + col] = acc[i][j][r];
            }
}

// ---------------------------------------------------------------- flash attention
// grid (16, 16), 512 threads. Block: q-tiles qt=bx and 31-bx (uniform 33 iters),
// TWO q-heads sharing one kv-head (K/V staging amortized 2x).
// Waves: w=tid>>6; wh=w>>2 selects head, wr=w&3 selects 16-row group.
__global__ __launch_bounds__(512) void flash_attn(const ushort_t* __restrict__ Q,
                                                  const ushort_t* __restrict__ Kp,
                                                  const ushort_t* __restrict__ Vt,
                                                  ushort_t* __restrict__ Y) {
    const int by = blockIdx.y;
    const int kh = by >> 1;
    const int hbase = kh * 4 + (by & 1) * 2;
    const int tid = threadIdx.x;
    const int w = tid >> 6, lane = tid & 63;
    const int wh = w >> 2, wr = w & 3;
    const int h = hbase + wh;
    const int quad = lane >> 4, l16 = lane & 15;

    __shared__ __align__(16) ushort_t Ks[64 * 136];    // keys x dims
    __shared__ __align__(16) ushort_t VtS[128 * 80];   // dims x keys
    __shared__ __align__(16) ushort_t Ps[8 * 16 * 80]; // per-wave P round-trip

#pragma unroll 1
    for (int phase = 0; phase < 2; phase++) {
        const int qt = (phase == 0) ? blockIdx.x : 31 - blockIdx.x;

        bf16x8 qf[4];
        {
            const ushort_t* qrow = Q + (size_t)(qt * 64 + wr * 16 + l16) * 4096 + h * 128 + quad * 8;
#pragma unroll
            for (int ks = 0; ks < 4; ks++) qf[ks] = *(const bf16x8*)(qrow + ks * 32);
        }

        f32x4 o[8] = {};
        float m_i[4], l_i[4];
#pragma unroll
        for (int r = 0; r < 4; r++) { m_i[r] = -1e30f; l_i[r] = 0.f; }

        const int ntiles = qt + 1;
        for (int j = 0; j < ntiles; j++) {
            const int t0 = j * 64;
            {   // K tile: 64x128 = 1024 16B-chunks over 512 threads
#pragma unroll
                for (int p = 0; p < 2; p++) {
                    int ck = p * 512 + tid;
                    int r = ck >> 4, c = (ck & 15) * 8;
                    uint4 d = *(const uint4*)(Kp + (size_t)(t0 + r) * 1024 + kh * 128 + c);
                    *(uint4*)(&Ks[r * 136 + c]) = d;
                }
            }
            {   // V^T tile: 128x64 = 1024 chunks
#pragma unroll
                for (int p = 0; p < 2; p++) {
                    int ck = p * 512 + tid;
                    int d = ck >> 3, c = (ck & 7) * 8;
                    uint4 v = *(const uint4*)(Vt + (size_t)(kh * 128 + d) * 2048 + t0 + c);
                    *(uint4*)(&VtS[d * 80 + c]) = v;
                }
            }
            __syncthreads();

            // S = Q @ K^T
            f32x4 s[4] = {};
#pragma unroll
            for (int ct = 0; ct < 4; ct++)
#pragma unroll
                for (int ks = 0; ks < 4; ks++) {
                    bf16x8 kf = *(const bf16x8*)(&Ks[(ct * 16 + l16) * 136 + ks * 32 + quad * 8]);
                    s[ct] = MFMA16(qf[ks], kf, s[ct]);
                }

            if (j == qt) {   // diagonal: causal mask
#pragma unroll
                for (int ct = 0; ct < 4; ct++)
#pragma unroll
                    for (int r = 0; r < 4; r++) {
                        int rg = wr * 16 + quad * 4 + r;
                        int cg = ct * 16 + l16;
                        if (cg > rg) s[ct][r] = -1e30f;
                    }
            }

            // online softmax (quad's 16 lanes share rows quad*4+r)
            float alpha[4];
#pragma unroll
            for (int r = 0; r < 4; r++) {
                float v = fmaxf(fmaxf(s[0][r], s[1][r]), fmaxf(s[2][r], s[3][r]));
                v = fmaxf(v, __shfl_xor(v, 1));
                v = fmaxf(v, __shfl_xor(v, 2));
                v = fmaxf(v, __shfl_xor(v, 4));
                v = fmaxf(v, __shfl_xor(v, 8));
                float mn = fmaxf(m_i[r], v);
                alpha[r] = __expf(m_i[r] - mn);
                m_i[r] = mn;
            }
            float rs[4] = {0.f, 0.f, 0.f, 0.f};
#pragma unroll
            for (int ct = 0; ct < 4; ct++)
#pragma unroll
                for (int r = 0; r < 4; r++) {
                    float p = __expf(s[ct][r] - m_i[r]);
                    s[ct][r] = p;
                    rs[r] += p;
                }
#pragma unroll
            for (int r = 0; r < 4; r++) {
                float v = rs[r];
                v += __shfl_xor(v, 1);
                v += __shfl_xor(v, 2);
                v += __shfl_xor(v, 4);
                v += __shfl_xor(v, 8);
                l_i[r] = alpha[r] * l_i[r] + v;
            }
#pragma unroll
            for (int n = 0; n < 8; n++)
#pragma unroll
                for (int r = 0; r < 4; r++) o[n][r] *= alpha[r];

            // P: D-layout -> A-layout via per-wave LDS region
#pragma unroll
            for (int ct = 0; ct < 4; ct++)
#pragma unroll
                for (int r = 0; r < 4; r++)
                    Ps[w * 1280 + (quad * 4 + r) * 80 + ct * 16 + l16] = f2bf(s[ct][r]);
            __syncthreads();

            // O += P (16x64) @ V (64x128)
#pragma unroll
            for (int ks2 = 0; ks2 < 2; ks2++) {
                bf16x8 pf = *(const bf16x8*)(&Ps[w * 1280 + l16 * 80 + ks2 * 32 + quad * 8]);
#pragma unroll
                for (int n = 0; n < 8; n++) {
                    bf16x8 vf = *(const bf16x8*)(&VtS[(n * 16 + l16) * 80 + ks2 * 32 + quad * 8]);
                    o[n] = MFMA16(pf, vf, o[n]);
                }
            }
            __syncthreads();
        }

        float inv[4];
#pragma unroll
        for (int r = 0; r < 4; r++) inv[r] = 1.0f / l_i[r];
#pragma unroll
        for (int n = 0; n < 8; n++)
#pragma unroll
            for (int r = 0; r < 4; r++) {
                int row = qt * 64 + wr * 16 + quad * 4 + r;
                int col = h * 128 + n * 16 + l16;
                Y[(size_t)row * 4096 + col] = f2bf(o[n][r] * inv[r]);
            }
    }
}

// ---------------------------------------------------------------- launch
extern "C" void kernel_launch(void* const* d_in, const int* in_sizes, int n_in,
                              void* d_out, int out_size, void* d_ws, size_t ws_size,
                              hipStream_t stream) {
    const float* x    = (const float*)d_in[0];
    const float* cosp = (const float*)d_in[1];
    const float* sinp = (const float*)d_in[2];
    const float* wq   = (const float*)d_in[3];
    const float* wk   = (const float*)d_in[4];
    const float* wv   = (const float*)d_in[5];
    const float* wo   = (const float*)d_in[6];
    float* out = (float*)d_out;

    // workspace (bf16 elems), 104 MB
    ushort_t* xb   = (ushort_t*)d_ws;
    ushort_t* qb   = xb  + (size_t)2048 * 4096;
    ushort_t* yb   = qb  + (size_t)2048 * 4096;
    ushort_t* kb   = yb  + (size_t)2048 * 4096;
    ushort_t* vtb  = kb  + (size_t)2048 * 1024;   // V^T (1024 x 2048)
    ushort_t* wkb  = vtb + (size_t)1024 * 2048;
    ushort_t* wvb  = wkb + (size_t)1024 * 4096;
    ushort_t* wbig = wvb + (size_t)1024 * 4096;   // wq, later overwritten by wo

    // 1) all input casts in one launch
    cast_multi<<<32768, 256, 0, stream>>>(x, wq, wk, wv, xb, wbig, wkb, wvb);

    // 2) fused QKV projection + RoPE + V-transpose
    {
        dim3 g(16, 48, 1);
        gemm_qkv<<<g, 256, 0, stream>>>(xb, wbig, wkb, wvb, qb, kb, vtb, cosp, sinp);
    }

    // 3) flash attention (2 heads/block, paired-causal q-tiles)
    {
        dim3 g(16, 16, 1);
        flash_attn<<<g, 512, 0, stream>>>(qb, kb, vtb, yb);
    }

    // 4) wo cast (overwrites wq copy — already consumed) + output projection
    cast_f32_bf16<<<16384, 256, 0, stream>>>(wo, wbig, 4096 * 4096 / 4);
    {
        dim3 g(16, 32, 1);
        gemm_bt<<<g, 256, 0, stream>>>(yb, wbig, out, 2048, 4096, 4096);
    }
}

// Round 4
// 530.882 us; speedup vs baseline: 1.7193x; 1.1097x over previous
//
#include <hip/hip_runtime.h>
#include <stdint.h>

typedef unsigned short ushort_t;
typedef __attribute__((ext_vector_type(8))) __bf16 bf16x8;
typedef __attribute__((ext_vector_type(4))) float f32x4;

#define MFMA16(a, b, c) __builtin_amdgcn_mfma_f32_16x16x32_bf16((a), (b), (c), 0, 0, 0)

__device__ __forceinline__ ushort_t f2bf(float f) {
    unsigned u = __float_as_uint(f);
    u += 0x7fffu + ((u >> 16) & 1u);   // round-to-nearest-even
    return (ushort_t)(u >> 16);
}

// async global->LDS 16B (m97 path). LDS dest must be wave-uniform base + lane*16.
typedef __attribute__((address_space(1))) const unsigned char g_u8;
typedef __attribute__((address_space(3))) unsigned char l_u8;
__device__ __forceinline__ void gload16(const void* g, void* l) {
    __builtin_amdgcn_global_load_lds((g_u8*)g, (l_u8*)(unsigned int)(uintptr_t)l, 16, 0, 0);
}

// ---------------------------------------------------------------- fused casts f32 -> bf16
__global__ __launch_bounds__(256) void cast_multi(const float* __restrict__ x,
                                                  const float* __restrict__ wq,
                                                  const float* __restrict__ wk,
                                                  const float* __restrict__ wv,
                                                  ushort_t* __restrict__ xb,
                                                  ushort_t* __restrict__ wqb,
                                                  ushort_t* __restrict__ wkb,
                                                  ushort_t* __restrict__ wvb) {
    int i = blockIdx.x * 256 + threadIdx.x;
    const float* in; ushort_t* out; int off;
    if (i < 2097152)      { in = x;  out = xb;  off = i; }
    else if (i < 6291456) { in = wq; out = wqb; off = i - 2097152; }
    else if (i < 7340032) { in = wk; out = wkb; off = i - 6291456; }
    else                  { in = wv; out = wvb; off = i - 7340032; }
    float4 v = ((const float4*)in)[off];
    ushort4 o;
    o.x = f2bf(v.x); o.y = f2bf(v.y); o.z = f2bf(v.z); o.w = f2bf(v.w);
    ((ushort4*)out)[off] = o;
}

__global__ __launch_bounds__(256) void cast_f32_bf16(const float* __restrict__ in,
                                                     ushort_t* __restrict__ out, int n4) {
    int i = blockIdx.x * 256 + threadIdx.x;
    if (i < n4) {
        float4 v = ((const float4*)in)[i];
        ushort4 o;
        o.x = f2bf(v.x); o.y = f2bf(v.y); o.z = f2bf(v.z); o.w = f2bf(v.w);
        ((ushort4*)out)[i] = o;
    }
}

// ---------------------------------------------------------------- BK=64 swizzled K-loop (shared)
// LDS tile = 128 rows x 64 cols bf16, stored as 16B chunks: chunk(row,kc) at
// slot row*8 + (kc ^ (row&7)). Staging: slot s = p*256+tid -> row=s>>3,
// kc=(s&7)^(row&7); LDS byte = s*16 (lane-contiguous per wave => gload16-legal).
// Frag read (row = base+l16): elem offset = row*64 + ((kc ^ (l16&7))<<3) -> 2-way banks.
#define GEMM_K_LOOP(Aarr, Barr, KDIM)                                                   \
    const ushort_t* aptr[4]; const ushort_t* bptr[4]; int ldsoff[4];                    \
    _Pragma("unroll")                                                                   \
    for (int p = 0; p < 4; p++) {                                                       \
        int s = p * 256 + tid;                                                          \
        int row = s >> 3;                                                               \
        int kc = (s & 7) ^ (row & 7);                                                   \
        aptr[p] = Aarr + (size_t)(bm + row) * (KDIM) + kc * 8;                          \
        bptr[p] = Barr + (size_t)(bn + row) * (KDIM) + kc * 8;                          \
        ldsoff[p] = s * 8;                                                              \
    }                                                                                   \
    const int r7 = l16 & 7;                                                             \
    for (int k0 = 0; k0 < (KDIM); k0 += 64) {                                           \
        _Pragma("unroll")                                                               \
        for (int p = 0; p < 4; p++) {                                                   \
            gload16(aptr[p] + k0, As + ldsoff[p]);                                      \
            gload16(bptr[p] + k0, Bs + ldsoff[p]);                                      \
        }                                                                               \
        __syncthreads();                                                                \
        _Pragma("unroll")                                                               \
        for (int ks2 = 0; ks2 < 2; ks2++) {                                             \
            bf16x8 af[4], bfr[4];                                                       \
            _Pragma("unroll")                                                           \
            for (int i = 0; i < 4; i++)                                                 \
                af[i] = *(const bf16x8*)(&As[(wm + i * 16 + l16) * 64 +                 \
                                             (((ks2 * 4 + quad) ^ r7) << 3)]);          \
            _Pragma("unroll")                                                           \
            for (int j = 0; j < 4; j++)                                                 \
                bfr[j] = *(const bf16x8*)(&Bs[(wn + j * 16 + l16) * 64 +                \
                                              (((ks2 * 4 + quad) ^ r7) << 3)]);         \
            _Pragma("unroll")                                                           \
            for (int i = 0; i < 4; i++)                                                 \
                _Pragma("unroll")                                                       \
                for (int j = 0; j < 4; j++)                                             \
                    acc[i][j] = MFMA16(af[i], bfr[j], acc[i][j]);                       \
        }                                                                               \
        __syncthreads();                                                                \
    }

// ---------------------------------------------------------------- fused QKV GEMM
// A (2048,4096) bf16. by<32: Q (+rope,*scale) -> qb; by<40: K (+rope) -> kb;
// else: V stored transposed -> vt (1024,2048).
__global__ __launch_bounds__(256) void gemm_qkv(const ushort_t* __restrict__ A,
                                                const ushort_t* __restrict__ Wq,
                                                const ushort_t* __restrict__ Wk,
                                                const ushort_t* __restrict__ Wv,
                                                ushort_t* __restrict__ Qo,
                                                ushort_t* __restrict__ Ko,
                                                ushort_t* __restrict__ VtO,
                                                const float* __restrict__ cosp,
                                                const float* __restrict__ sinp) {
    const int by = blockIdx.y;
    const ushort_t* B;
    int region, bn;
    if (by < 32)      { region = 0; B = Wq; bn = by * 128; }
    else if (by < 40) { region = 1; B = Wk; bn = (by - 32) * 128; }
    else              { region = 2; B = Wv; bn = (by - 40) * 128; }
    const int bm = blockIdx.x * 128;

    __shared__ __align__(16) ushort_t As[128 * 64];
    __shared__ __align__(16) ushort_t Bs[128 * 64];
    const int tid = threadIdx.x;
    const int w = tid >> 6, lane = tid & 63;
    const int quad = lane >> 4, l16 = lane & 15;
    const int wm = (w >> 1) * 64, wn = (w & 1) * 64;
    f32x4 acc[4][4] = {};

    GEMM_K_LOOP(A, B, 4096)

    // epilogue. D layout: col = lane&15, row = quad*4+reg [m89/m91]
    const float qscale = 0.08838834764831845f;  // 1/sqrt(128)
    if (region < 2) {
        ushort_t* C = (region == 0) ? Qo : Ko;
        const int Nc = (region == 0) ? 4096 : 1024;
        const float scl = (region == 0) ? qscale : 1.0f;
#pragma unroll
        for (int i = 0; i < 4; i++)
#pragma unroll
            for (int j = 0; j < 4; j++) {
                const int col = bn + wn + j * 16 + l16;
                const int pj = (col & 127) >> 1;
#pragma unroll
                for (int r = 0; r < 4; r++) {
                    const int row = bm + wm + i * 16 + quad * 4 + r;
                    float v = acc[i][j][r];
                    float p = __shfl_xor(v, 1);         // partner column (col^1)
                    float c = cosp[row * 64 + pj], s = sinp[row * 64 + pj];
                    float res = (col & 1) ? fmaf(p, s, v * c)
                                          : (v * c - p * s);
                    C[(size_t)row * Nc + col] = f2bf(res * scl);
                }
            }
    } else {
        // V^T: VtO[dim][token], reg r spans 4 consecutive tokens -> 8B packed store
#pragma unroll
        for (int i = 0; i < 4; i++) {
            const int rowb = bm + wm + i * 16 + quad * 4;
#pragma unroll
            for (int j = 0; j < 4; j++) {
                const int col = bn + wn + j * 16 + l16;
                ushort4 pk;
                pk.x = f2bf(acc[i][j][0]); pk.y = f2bf(acc[i][j][1]);
                pk.z = f2bf(acc[i][j][2]); pk.w = f2bf(acc[i][j][3]);
                *(ushort4*)(VtO + (size_t)col * 2048 + rowb) = pk;
            }
        }
    }
}

// ---------------------------------------------------------------- GEMM: C = A @ B^T (wo, fp32 out)
__global__ __launch_bounds__(256) void gemm_bt(const ushort_t* __restrict__ A,
                                               const ushort_t* __restrict__ B,
                                               float* __restrict__ C,
                                               int M, int N, int K) {
    const int bm = blockIdx.x * 128, bn = blockIdx.y * 128;
    __shared__ __align__(16) ushort_t As[128 * 64];
    __shared__ __align__(16) ushort_t Bs[128 * 64];
    const int tid = threadIdx.x;
    const int w = tid >> 6, lane = tid & 63;
    const int quad = lane >> 4, l16 = lane & 15;
    const int wm = (w >> 1) * 64, wn = (w & 1) * 64;
    f32x4 acc[4][4] = {};

    GEMM_K_LOOP(A, B, K)

#pragma unroll
    for (int i = 0; i < 4; i++)
#pragma unroll
        for (int j = 0; j < 4; j++)
#pragma unroll
            for (int r = 0; r < 4; r++) {
                int row = bm + wm + i * 16 + quad * 4 + r;
                int col = bn + wn + j * 16 + l16;
                C[(size_t)row * N + col] = acc[i][j][r];
            }
}

// ---------------------------------------------------------------- flash attention
// grid (16, 16), 512 threads. Block: q-tiles qt=bx and 31-bx (uniform 33 iters),
// two q-heads sharing one kv-head. w=tid>>6; wh=w>>2 head, wr=w&3 row-group.
__global__ __launch_bounds__(512) void flash_attn(const ushort_t* __restrict__ Q,
                                                  const ushort_t* __restrict__ Kp,
                                                  const ushort_t* __restrict__ Vt,
                                                  ushort_t* __restrict__ Y) {
    const int by = blockIdx.y;
    const int kh = by >> 1;
    const int hbase = kh * 4 + (by & 1) * 2;
    const int tid = threadIdx.x;
    const int w = tid >> 6, lane = tid & 63;
    const int wh = w >> 2, wr = w & 3;
    const int h = hbase + wh;
    const int quad = lane >> 4, l16 = lane & 15;

    __shared__ __align__(16) ushort_t Ks[64 * 136];    // keys x dims (2-way banks)
    __shared__ __align__(16) ushort_t VtS[128 * 88];   // dims x keys, stride 88 (2-way)
    __shared__ __align__(16) ushort_t Ps[8 * 16 * 88]; // per-wave P round-trip, stride 88

    // ones B-fragment for MFMA row-sum (P @ 1)
    bf16x8 ones;
#pragma unroll
    for (int e = 0; e < 8; e++) ((ushort_t*)&ones)[e] = 0x3F80;  // bf16 1.0

#pragma unroll 1
    for (int phase = 0; phase < 2; phase++) {
        const int qt = (phase == 0) ? blockIdx.x : 31 - blockIdx.x;

        bf16x8 qf[4];
        {
            const ushort_t* qrow = Q + (size_t)(qt * 64 + wr * 16 + l16) * 4096 + h * 128 + quad * 8;
#pragma unroll
            for (int ks = 0; ks < 4; ks++) qf[ks] = *(const bf16x8*)(qrow + ks * 32);
        }

        f32x4 o[8] = {};
        f32x4 lacc = {};
        float m_i[4];
#pragma unroll
        for (int r = 0; r < 4; r++) m_i[r] = -1e30f;

        const int ntiles = qt + 1;
        for (int j = 0; j < ntiles; j++) {
            const int t0 = j * 64;
            {   // K tile: 64x128 = 1024 16B-chunks over 512 threads
#pragma unroll
                for (int p = 0; p < 2; p++) {
                    int ck = p * 512 + tid;
                    int r = ck >> 4, c = (ck & 15) * 8;
                    uint4 d = *(const uint4*)(Kp + (size_t)(t0 + r) * 1024 + kh * 128 + c);
                    *(uint4*)(&Ks[r * 136 + c]) = d;
                }
            }
            {   // V^T tile: 128x64 = 1024 chunks
#pragma unroll
                for (int p = 0; p < 2; p++) {
                    int ck = p * 512 + tid;
                    int d = ck >> 3, c = (ck & 7) * 8;
                    uint4 v = *(const uint4*)(Vt + (size_t)(kh * 128 + d) * 2048 + t0 + c);
                    *(uint4*)(&VtS[d * 88 + c]) = v;
                }
            }
            __syncthreads();

            // S = Q @ K^T
            f32x4 s[4] = {};
#pragma unroll
            for (int ct = 0; ct < 4; ct++)
#pragma unroll
                for (int ks = 0; ks < 4; ks++) {
                    bf16x8 kf = *(const bf16x8*)(&Ks[(ct * 16 + l16) * 136 + ks * 32 + quad * 8]);
                    s[ct] = MFMA16(qf[ks], kf, s[ct]);
                }

            if (j == qt) {   // diagonal: causal mask
#pragma unroll
                for (int ct = 0; ct < 4; ct++)
#pragma unroll
                    for (int r = 0; r < 4; r++) {
                        int rg = wr * 16 + quad * 4 + r;
                        int cg = ct * 16 + l16;
                        if (cg > rg) s[ct][r] = -1e30f;
                    }
            }

            // online softmax max-update (quad's 16 lanes share rows quad*4+r)
            float alpha[4];
#pragma unroll
            for (int r = 0; r < 4; r++) {
                float v = fmaxf(fmaxf(s[0][r], s[1][r]), fmaxf(s[2][r], s[3][r]));
                v = fmaxf(v, __shfl_xor(v, 1));
                v = fmaxf(v, __shfl_xor(v, 2));
                v = fmaxf(v, __shfl_xor(v, 4));
                v = fmaxf(v, __shfl_xor(v, 8));
                float mn = fmaxf(m_i[r], v);
                alpha[r] = __expf(m_i[r] - mn);
                m_i[r] = mn;
            }
#pragma unroll
            for (int ct = 0; ct < 4; ct++)
#pragma unroll
                for (int r = 0; r < 4; r++)
                    s[ct][r] = __expf(s[ct][r] - m_i[r]);
            // rescale running O and running row-sum
#pragma unroll
            for (int n = 0; n < 8; n++)
#pragma unroll
                for (int r = 0; r < 4; r++) o[n][r] *= alpha[r];
#pragma unroll
            for (int r = 0; r < 4; r++) lacc[r] *= alpha[r];

            // P: D-layout -> A-layout via per-wave LDS region (wave-private: no barrier)
#pragma unroll
            for (int ct = 0; ct < 4; ct++)
#pragma unroll
                for (int r = 0; r < 4; r++)
                    Ps[w * 1408 + (quad * 4 + r) * 88 + ct * 16 + l16] = f2bf(s[ct][r]);
            __threadfence_block();   // in-wave LDS RAW ordering; no s_barrier needed

            // O += P (16x64) @ V (64x128); row-sum l += P @ 1 via MFMA
#pragma unroll
            for (int ks2 = 0; ks2 < 2; ks2++) {
                bf16x8 pf = *(const bf16x8*)(&Ps[w * 1408 + l16 * 88 + ks2 * 32 + quad * 8]);
                lacc = MFMA16(pf, ones, lacc);
#pragma unroll
                for (int n = 0; n < 8; n++) {
                    bf16x8 vf = *(const bf16x8*)(&VtS[(n * 16 + l16) * 88 + ks2 * 32 + quad * 8]);
                    o[n] = MFMA16(pf, vf, o[n]);
                }
            }
            __syncthreads();
        }

        float inv[4];
#pragma unroll
        for (int r = 0; r < 4; r++) inv[r] = 1.0f / lacc[r];
#pragma unroll
        for (int n = 0; n < 8; n++)
#pragma unroll
            for (int r = 0; r < 4; r++) {
                int row = qt * 64 + wr * 16 + quad * 4 + r;
                int col = h * 128 + n * 16 + l16;
                Y[(size_t)row * 4096 + col] = f2bf(o[n][r] * inv[r]);
            }
    }
}

// ---------------------------------------------------------------- launch
extern "C" void kernel_launch(void* const* d_in, const int* in_sizes, int n_in,
                              void* d_out, int out_size, void* d_ws, size_t ws_size,
                              hipStream_t stream) {
    const float* x    = (const float*)d_in[0];
    const float* cosp = (const float*)d_in[1];
    const float* sinp = (const float*)d_in[2];
    const float* wq   = (const float*)d_in[3];
    const float* wk   = (const float*)d_in[4];
    const float* wv   = (const float*)d_in[5];
    const float* wo   = (const float*)d_in[6];
    float* out = (float*)d_out;

    // workspace (bf16 elems), 104 MB
    ushort_t* xb   = (ushort_t*)d_ws;
    ushort_t* qb   = xb  + (size_t)2048 * 4096;
    ushort_t* yb   = qb  + (size_t)2048 * 4096;
    ushort_t* kb   = yb  + (size_t)2048 * 4096;
    ushort_t* vtb  = kb  + (size_t)2048 * 1024;   // V^T (1024 x 2048)
    ushort_t* wkb  = vtb + (size_t)1024 * 2048;
    ushort_t* wvb  = wkb + (size_t)1024 * 4096;
    ushort_t* wbig = wvb + (size_t)1024 * 4096;   // wq, later overwritten by wo

    // 1) all input casts in one launch
    cast_multi<<<32768, 256, 0, stream>>>(x, wq, wk, wv, xb, wbig, wkb, wvb);

    // 2) fused QKV projection + RoPE + V-transpose
    {
        dim3 g(16, 48, 1);
        gemm_qkv<<<g, 256, 0, stream>>>(xb, wbig, wkb, wvb, qb, kb, vtb, cosp, sinp);
    }

    // 3) flash attention (2 heads/block, paired-causal q-tiles)
    {
        dim3 g(16, 16, 1);
        flash_attn<<<g, 512, 0, stream>>>(qb, kb, vtb, yb);
    }

    // 4) wo cast (overwrites wq copy — already consumed) + output projection
    cast_f32_bf16<<<16384, 256, 0, stream>>>(wo, wbig, 4096 * 4096 / 4);
    {
        dim3 g(16, 32, 1);
        gemm_bt<<<g, 256, 0, stream>>>(yb, wbig, out, 2048, 4096, 4096);
    }
}

// Round 5
// 472.199 us; speedup vs baseline: 1.9330x; 1.1243x over previous
//
#include <hip/hip_runtime.h>
#include <stdint.h>

typedef unsigned short ushort_t;
typedef __attribute__((ext_vector_type(8))) __bf16 bf16x8;
typedef __attribute__((ext_vector_type(4))) float f32x4;
typedef __attribute__((ext_vector_type(16))) float f32x16;

#define MFMA16(a, b, c) __builtin_amdgcn_mfma_f32_16x16x32_bf16((a), (b), (c), 0, 0, 0)
#define MFMA32(a, b, c) __builtin_amdgcn_mfma_f32_32x32x16_bf16((a), (b), (c), 0, 0, 0)

__device__ __forceinline__ ushort_t f2bf(float f) {
    unsigned u = __float_as_uint(f);
    u += 0x7fffu + ((u >> 16) & 1u);   // round-to-nearest-even
    return (ushort_t)(u >> 16);
}

// async global->LDS 16B (m97 path). LDS dest must be wave-uniform base + lane*16.
typedef __attribute__((address_space(1))) const unsigned char g_u8;
typedef __attribute__((address_space(3))) unsigned char l_u8;
__device__ __forceinline__ void gload16(const void* g, void* l) {
    __builtin_amdgcn_global_load_lds((g_u8*)g, (l_u8*)(unsigned int)(uintptr_t)l, 16, 0, 0);
}

// ---------------------------------------------------------------- fused casts f32 -> bf16
__global__ __launch_bounds__(256) void cast_multi(const float* __restrict__ x,
                                                  const float* __restrict__ wq,
                                                  const float* __restrict__ wk,
                                                  const float* __restrict__ wv,
                                                  ushort_t* __restrict__ xb,
                                                  ushort_t* __restrict__ wqb,
                                                  ushort_t* __restrict__ wkb,
                                                  ushort_t* __restrict__ wvb) {
    int i = blockIdx.x * 256 + threadIdx.x;
    const float* in; ushort_t* out; int off;
    if (i < 2097152)      { in = x;  out = xb;  off = i; }
    else if (i < 6291456) { in = wq; out = wqb; off = i - 2097152; }
    else if (i < 7340032) { in = wk; out = wkb; off = i - 6291456; }
    else                  { in = wv; out = wvb; off = i - 7340032; }
    float4 v = ((const float4*)in)[off];
    ushort4 o;
    o.x = f2bf(v.x); o.y = f2bf(v.y); o.z = f2bf(v.z); o.w = f2bf(v.w);
    ((ushort4*)out)[off] = o;
}

__global__ __launch_bounds__(256) void cast_f32_bf16(const float* __restrict__ in,
                                                     ushort_t* __restrict__ out, int n4) {
    int i = blockIdx.x * 256 + threadIdx.x;
    if (i < n4) {
        float4 v = ((const float4*)in)[i];
        ushort4 o;
        o.x = f2bf(v.x); o.y = f2bf(v.y); o.z = f2bf(v.z); o.w = f2bf(v.w);
        ((ushort4*)out)[i] = o;
    }
}

// ---------------------------------------------------------------- BK=64 swizzled K-loop, 32x32x16 MFMA
// LDS tile 128 rows x 64 cols bf16 as 16B chunks: chunk(row,kc) at slot row*8+(kc^(row&7)).
// Staging slot s=p*256+tid (lane-contiguous 16B => gload16-legal); zero bank conflicts (r4-measured).
// Wave tile 64x64 = 2x2 of 32x32; A-frag: m=lane&31, k=(lane>>5)*8+j; 4 k-steps of 16.
#define GEMM_K_LOOP(Aarr, Barr, KDIM)                                                   \
    const ushort_t* aptr[4]; const ushort_t* bptr[4]; int ldsoff[4];                    \
    _Pragma("unroll")                                                                   \
    for (int p = 0; p < 4; p++) {                                                       \
        int s = p * 256 + tid;                                                          \
        int row = s >> 3;                                                               \
        int kc = (s & 7) ^ (row & 7);                                                   \
        aptr[p] = Aarr + (size_t)(bm + row) * (KDIM) + kc * 8;                          \
        bptr[p] = Barr + (size_t)(bn + row) * (KDIM) + kc * 8;                          \
        ldsoff[p] = s * 8;                                                              \
    }                                                                                   \
    const int l32 = lane & 31, hi = lane >> 5, r7 = l32 & 7;                            \
    for (int k0 = 0; k0 < (KDIM); k0 += 64) {                                           \
        _Pragma("unroll")                                                               \
        for (int p = 0; p < 4; p++) {                                                   \
            gload16(aptr[p] + k0, As + ldsoff[p]);                                      \
            gload16(bptr[p] + k0, Bs + ldsoff[p]);                                      \
        }                                                                               \
        __syncthreads();                                                                \
        _Pragma("unroll")                                                               \
        for (int ks = 0; ks < 4; ks++) {                                                \
            const int swz = ((ks * 2 + hi) ^ r7) << 3;                                  \
            bf16x8 a0 = *(const bf16x8*)(&As[(wm + l32) * 64 + swz]);                   \
            bf16x8 a1 = *(const bf16x8*)(&As[(wm + 32 + l32) * 64 + swz]);              \
            bf16x8 b0 = *(const bf16x8*)(&Bs[(wn + l32) * 64 + swz]);                   \
            bf16x8 b1 = *(const bf16x8*)(&Bs[(wn + 32 + l32) * 64 + swz]);              \
            acc[0][0] = MFMA32(a0, b0, acc[0][0]);                                      \
            acc[0][1] = MFMA32(a0, b1, acc[0][1]);                                      \
            acc[1][0] = MFMA32(a1, b0, acc[1][0]);                                      \
            acc[1][1] = MFMA32(a1, b1, acc[1][1]);                                      \
        }                                                                               \
        __syncthreads();                                                                \
    }

// ---------------------------------------------------------------- fused QKV GEMM (+ optional wo cast tail)
// by<32: Q (+rope,*scale) -> qb; by<40: K (+rope) -> kb; by<48: V transposed -> vt;
// by>=48 (only when fuse_wo): cast wo f32 -> wob bf16 (1024 light blocks fill the tail).
__global__ __launch_bounds__(256, 3) void gemm_qkv(const ushort_t* __restrict__ A,
                                                   const ushort_t* __restrict__ Wq,
                                                   const ushort_t* __restrict__ Wk,
                                                   const ushort_t* __restrict__ Wv,
                                                   ushort_t* __restrict__ Qo,
                                                   ushort_t* __restrict__ Ko,
                                                   ushort_t* __restrict__ VtO,
                                                   const float* __restrict__ cosp,
                                                   const float* __restrict__ sinp,
                                                   const float* __restrict__ wo,
                                                   ushort_t* __restrict__ wob) {
    const int by = blockIdx.y;
    const int tid = threadIdx.x;

    if (by >= 48) {   // wo cast tail: 1024 blocks x 4096 float4
        const int ci = (by - 48) * gridDim.x + blockIdx.x;
        const float4* src = (const float4*)wo;
        ushort4* dst = (ushort4*)wob;
        int base = ci * 4096 + tid;
#pragma unroll
        for (int p = 0; p < 16; p++) {
            float4 v = src[base + p * 256];
            ushort4 o;
            o.x = f2bf(v.x); o.y = f2bf(v.y); o.z = f2bf(v.z); o.w = f2bf(v.w);
            dst[base + p * 256] = o;
        }
        return;
    }

    const ushort_t* B;
    int region, bn;
    if (by < 32)      { region = 0; B = Wq; bn = by * 128; }
    else if (by < 40) { region = 1; B = Wk; bn = (by - 32) * 128; }
    else              { region = 2; B = Wv; bn = (by - 40) * 128; }
    const int bm = blockIdx.x * 128;

    __shared__ __align__(16) ushort_t As[128 * 64];
    __shared__ __align__(16) ushort_t Bs[128 * 64];
    const int w = tid >> 6, lane = tid & 63;
    const int wm = (w >> 1) * 64, wn = (w & 1) * 64;
    f32x16 acc[2][2] = {};

    GEMM_K_LOOP(A, B, 4096)

    // D layout: col = lane&31, row = (reg&3) + 8*(reg>>2) + 4*(lane>>5)  [m74/m101]
    const float qscale = 0.08838834764831845f;  // 1/sqrt(128)
    if (region < 2) {
        ushort_t* C = (region == 0) ? Qo : Ko;
        const int Nc = (region == 0) ? 4096 : 1024;
        const float scl = (region == 0) ? qscale : 1.0f;
#pragma unroll
        for (int i = 0; i < 2; i++)
#pragma unroll
            for (int j = 0; j < 2; j++) {
                const int col = bn + wn + j * 32 + l32;
                const int pj = (col & 127) >> 1;
#pragma unroll
                for (int r = 0; r < 16; r++) {
                    const int row = bm + wm + i * 32 + (r & 3) + 8 * (r >> 2) + 4 * hi;
                    float v = acc[i][j][r];
                    float p = __shfl_xor(v, 1);     // partner column (col^1)
                    float c = cosp[row * 64 + pj], s = sinp[row * 64 + pj];
                    float res = (col & 1) ? fmaf(p, s, v * c)   // odd: x1*s + x2*c
                                          : (v * c - p * s);    // even: x1*c - x2*s
                    C[(size_t)row * Nc + col] = f2bf(res * scl);
                }
            }
    } else {
        // V^T: VtO[dim][token]; regs g*4..g*4+3 are 4 consecutive tokens -> 8B packed store
#pragma unroll
        for (int i = 0; i < 2; i++)
#pragma unroll
            for (int j = 0; j < 2; j++) {
                const int col = bn + wn + j * 32 + l32;   // dim
#pragma unroll
                for (int g = 0; g < 4; g++) {
                    const int rowb = bm + wm + i * 32 + g * 8 + 4 * hi;  // token base
                    ushort4 pk;
                    pk.x = f2bf(acc[i][j][g * 4 + 0]);
                    pk.y = f2bf(acc[i][j][g * 4 + 1]);
                    pk.z = f2bf(acc[i][j][g * 4 + 2]);
                    pk.w = f2bf(acc[i][j][g * 4 + 3]);
                    *(ushort4*)(VtO + (size_t)col * 2048 + rowb) = pk;
                }
            }
    }
}

// ---------------------------------------------------------------- GEMM: C = A @ B^T (wo, fp32 out)
__global__ __launch_bounds__(256, 3) void gemm_bt(const ushort_t* __restrict__ A,
                                                  const ushort_t* __restrict__ B,
                                                  float* __restrict__ C,
                                                  int M, int N, int K) {
    const int bm = blockIdx.x * 128, bn = blockIdx.y * 128;
    __shared__ __align__(16) ushort_t As[128 * 64];
    __shared__ __align__(16) ushort_t Bs[128 * 64];
    const int tid = threadIdx.x;
    const int w = tid >> 6, lane = tid & 63;
    const int wm = (w >> 1) * 64, wn = (w & 1) * 64;
    f32x16 acc[2][2] = {};

    GEMM_K_LOOP(A, B, K)

#pragma unroll
    for (int i = 0; i < 2; i++)
#pragma unroll
        for (int j = 0; j < 2; j++) {
            const int col = bn + wn + j * 32 + l32;
#pragma unroll
            for (int r = 0; r < 16; r++) {
                const int row = bm + wm + i * 32 + (r & 3) + 8 * (r >> 2) + 4 * hi;
                C[(size_t)row * N + col] = acc[i][j][r];
            }
        }
}

// ---------------------------------------------------------------- flash attention
// grid (16, 32), 256 threads, 1 head/block => 512 blocks = 2/CU (co-scheduling).
// Block handles q-tiles qt=bx and 31-bx (uniform 33 iters). Wave w owns rows w*16..w*16+15.
__global__ __launch_bounds__(256) void flash_attn(const ushort_t* __restrict__ Q,
                                                  const ushort_t* __restrict__ Kp,
                                                  const ushort_t* __restrict__ Vt,
                                                  ushort_t* __restrict__ Y) {
    const int h = blockIdx.y, kh = h >> 2;
    const int tid = threadIdx.x;
    const int w = tid >> 6, lane = tid & 63;
    const int quad = lane >> 4, l16 = lane & 15;

    __shared__ __align__(16) ushort_t Ks[64 * 136];    // keys x dims
    __shared__ __align__(16) ushort_t VtS[128 * 88];   // dims x keys (2-way banks)
    __shared__ __align__(16) ushort_t Ps[4 * 16 * 88]; // per-wave P round-trip

    bf16x8 ones;
#pragma unroll
    for (int e = 0; e < 8; e++) ((ushort_t*)&ones)[e] = 0x3F80;  // bf16 1.0

#pragma unroll 1
    for (int phase = 0; phase < 2; phase++) {
        const int qt = (phase == 0) ? blockIdx.x : 31 - blockIdx.x;

        bf16x8 qf[4];
        {
            const ushort_t* qrow = Q + (size_t)(qt * 64 + w * 16 + l16) * 4096 + h * 128 + quad * 8;
#pragma unroll
            for (int ks = 0; ks < 4; ks++) qf[ks] = *(const bf16x8*)(qrow + ks * 32);
        }

        f32x4 o[8] = {};
        f32x4 lacc = {};
        float m_i[4];
#pragma unroll
        for (int r = 0; r < 4; r++) m_i[r] = -1e30f;

        const int ntiles = qt + 1;
        for (int j = 0; j < ntiles; j++) {
            const int t0 = j * 64;
            {   // K tile: 64x128 = 1024 16B-chunks over 256 threads
#pragma unroll
                for (int p = 0; p < 4; p++) {
                    int ck = p * 256 + tid;
                    int r = ck >> 4, c = (ck & 15) * 8;
                    uint4 d = *(const uint4*)(Kp + (size_t)(t0 + r) * 1024 + kh * 128 + c);
                    *(uint4*)(&Ks[r * 136 + c]) = d;
                }
            }
            {   // V^T tile: 128x64 = 1024 chunks
#pragma unroll
                for (int p = 0; p < 4; p++) {
                    int ck = p * 256 + tid;
                    int d = ck >> 3, c = (ck & 7) * 8;
                    uint4 v = *(const uint4*)(Vt + (size_t)(kh * 128 + d) * 2048 + t0 + c);
                    *(uint4*)(&VtS[d * 88 + c]) = v;
                }
            }
            __syncthreads();

            // S = Q @ K^T
            f32x4 s[4] = {};
#pragma unroll
            for (int ct = 0; ct < 4; ct++)
#pragma unroll
                for (int ks = 0; ks < 4; ks++) {
                    bf16x8 kf = *(const bf16x8*)(&Ks[(ct * 16 + l16) * 136 + ks * 32 + quad * 8]);
                    s[ct] = MFMA16(qf[ks], kf, s[ct]);
                }

            if (j == qt) {   // diagonal: causal mask
#pragma unroll
                for (int ct = 0; ct < 4; ct++)
#pragma unroll
                    for (int r = 0; r < 4; r++) {
                        int rg = w * 16 + quad * 4 + r;
                        int cg = ct * 16 + l16;
                        if (cg > rg) s[ct][r] = -1e30f;
                    }
            }

            // online softmax (quad's 16 lanes share rows quad*4+r)
            float alpha[4];
#pragma unroll
            for (int r = 0; r < 4; r++) {
                float v = fmaxf(fmaxf(s[0][r], s[1][r]), fmaxf(s[2][r], s[3][r]));
                v = fmaxf(v, __shfl_xor(v, 1));
                v = fmaxf(v, __shfl_xor(v, 2));
                v = fmaxf(v, __shfl_xor(v, 4));
                v = fmaxf(v, __shfl_xor(v, 8));
                float mn = fmaxf(m_i[r], v);
                alpha[r] = __expf(m_i[r] - mn);
                m_i[r] = mn;
            }
#pragma unroll
            for (int ct = 0; ct < 4; ct++)
#pragma unroll
                for (int r = 0; r < 4; r++)
                    s[ct][r] = __expf(s[ct][r] - m_i[r]);
#pragma unroll
            for (int n = 0; n < 8; n++)
#pragma unroll
                for (int r = 0; r < 4; r++) o[n][r] *= alpha[r];
#pragma unroll
            for (int r = 0; r < 4; r++) lacc[r] *= alpha[r];

            // P: D-layout -> A-layout via per-wave LDS region (wave-private: no barrier)
#pragma unroll
            for (int ct = 0; ct < 4; ct++)
#pragma unroll
                for (int r = 0; r < 4; r++)
                    Ps[w * 1408 + (quad * 4 + r) * 88 + ct * 16 + l16] = f2bf(s[ct][r]);
            __threadfence_block();

            // O += P (16x64) @ V (64x128); row-sum l += P @ 1 via MFMA
#pragma unroll
            for (int ks2 = 0; ks2 < 2; ks2++) {
                bf16x8 pf = *(const bf16x8*)(&Ps[w * 1408 + l16 * 88 + ks2 * 32 + quad * 8]);
                lacc = MFMA16(pf, ones, lacc);
#pragma unroll
                for (int n = 0; n < 8; n++) {
                    bf16x8 vf = *(const bf16x8*)(&VtS[(n * 16 + l16) * 88 + ks2 * 32 + quad * 8]);
                    o[n] = MFMA16(pf, vf, o[n]);
                }
            }
            __syncthreads();
        }

        float inv[4];
#pragma unroll
        for (int r = 0; r < 4; r++) inv[r] = 1.0f / lacc[r];
#pragma unroll
        for (int n = 0; n < 8; n++)
#pragma unroll
            for (int r = 0; r < 4; r++) {
                int row = qt * 64 + w * 16 + quad * 4 + r;
                int col = h * 128 + n * 16 + l16;
                Y[(size_t)row * 4096 + col] = f2bf(o[n][r] * inv[r]);
            }
    }
}

// ---------------------------------------------------------------- launch
extern "C" void kernel_launch(void* const* d_in, const int* in_sizes, int n_in,
                              void* d_out, int out_size, void* d_ws, size_t ws_size,
                              hipStream_t stream) {
    const float* x    = (const float*)d_in[0];
    const float* cosp = (const float*)d_in[1];
    const float* sinp = (const float*)d_in[2];
    const float* wq   = (const float*)d_in[3];
    const float* wk   = (const float*)d_in[4];
    const float* wv   = (const float*)d_in[5];
    const float* wo   = (const float*)d_in[6];
    float* out = (float*)d_out;

    // workspace (bf16 elems)
    ushort_t* xb   = (ushort_t*)d_ws;
    ushort_t* qb   = xb  + (size_t)2048 * 4096;
    ushort_t* yb   = qb  + (size_t)2048 * 4096;
    ushort_t* kb   = yb  + (size_t)2048 * 4096;
    ushort_t* vtb  = kb  + (size_t)2048 * 1024;   // V^T (1024 x 2048)
    ushort_t* wkb  = vtb + (size_t)1024 * 2048;
    ushort_t* wvb  = wkb + (size_t)1024 * 4096;
    ushort_t* wbig = wvb + (size_t)1024 * 4096;   // wq (and wo if !fuse_wo)
    ushort_t* wob  = wbig + (size_t)4096 * 4096;  // separate wo buffer (fused path)
    const size_t need_fused = (size_t)(wob + (size_t)4096 * 4096 - xb) * sizeof(ushort_t);
    const bool fuse_wo = ws_size >= need_fused;

    // 1) input casts (x, wq, wk, wv)
    cast_multi<<<32768, 256, 0, stream>>>(x, wq, wk, wv, xb, wbig, wkb, wvb);

    // 2) fused QKV projection + RoPE + V-transpose (+ wo cast in tail if room)
    {
        dim3 g(16, fuse_wo ? 112 : 48, 1);
        gemm_qkv<<<g, 256, 0, stream>>>(xb, wbig, wkb, wvb, qb, kb, vtb, cosp, sinp,
                                        wo, fuse_wo ? wob : wbig);
    }

    // 3) flash attention (1 head/block, 2 blocks/CU, paired-causal q-tiles)
    {
        dim3 g(16, 32, 1);
        flash_attn<<<g, 256, 0, stream>>>(qb, kb, vtb, yb);
    }

    // 4) output projection (wo cast separately only if it didn't fit in ws)
    const ushort_t* wo_b = fuse_wo ? wob : wbig;
    if (!fuse_wo)
        cast_f32_bf16<<<16384, 256, 0, stream>>>(wo, wbig, 4096 * 4096 / 4);
    {
        dim3 g(16, 32, 1);
        gemm_bt<<<g, 256, 0, stream>>>(yb, wo_b, out, 2048, 4096, 4096);
    }
}